// Round 9
// baseline (258.827 us; speedup 1.0000x reference)
//
#include <hip/hip_runtime.h>
#include <math.h>

// Problem constants (from setup_inputs)
#define T_TOTAL 2097152
#define A_DIM   18
#define GAMMA_D 0.99

#define CHUNK 256
#define NC    (T_TOTAL / CHUNK)        // 8192 chunks
#define KTR   14                       // G^14 ~ 2e-16, G = 0.99^256 ~ 0.076
#define CPB   4                        // chunks per block
#define NB    (NC / CPB)               // 2048 blocks
#define BLK   512                      // 8 waves; 2 rows/thread

// Compile-time powers of gamma (replaces ocml pow: ~300 f64 ops + ~40 VGPRs
// of scratch pressure per call; differs from correctly-rounded pow by <=6 ulp,
// ~1e-15 relative — invisible after f32 rounding of the final scalar).
constexpr double Gp1   = GAMMA_D;
constexpr double Gp2   = Gp1 * Gp1;
constexpr double Gp4   = Gp2 * Gp2;      // g^4
constexpr double Gp8   = Gp4 * Gp4;
constexpr double Gp16  = Gp8 * Gp8;
constexpr double Gp32  = Gp16 * Gp16;
constexpr double Gp64  = Gp32 * Gp32;
constexpr double Gp128 = Gp64 * Gp64;
constexpr double Gp256 = Gp128 * Gp128;  // g^256 (per-chunk decay)
constexpr double IG    = 1.0 / GAMMA_D;

// ---------------------------------------------------------------------------
// Fused main kernel (R6 phase structure = proven correct; atomic epilogue
// REVERTED to partials array — R6/R7 counters showed ~100+ us serialized tail
// from 6144 same-address f64 atomics). Latency-focused changes:
//   - __launch_bounds__(512, 8): VGPR <=64, up to 8 waves/SIMD resident
//   - no ocml pow anywhere (constexpr chains + 6-mult bit-product for w4)
//   - ep_rs loads issued before weight loads (in-order vmcnt queue: phase 1
//     waits on the OLDEST loads, weight stream stays in flight)
__global__ __launch_bounds__(BLK, 8)
void k_mega(const float* __restrict__ wgt, const int* __restrict__ act,
            const float* __restrict__ r, double* __restrict__ partials) {
    __shared__ double ldsL[17];               // window chunk-sums
    __shared__ double ldsD[CPB * CHUNK];      // d for the block's 1024 rows (8 KB)
    __shared__ double red[24];
    const int tid  = threadIdx.x;
    const int lane = tid & 63, wv = tid >> 6;      // wv in 0..7
    const int c0   = blockIdx.x * CPB;
    const double g = GAMMA_D;
    // w4 = g^(4*lane) via bit-product (6 mult + 6 select, exact to ~6 ulp)
    double w4 = 1.0;
    w4 *= (lane & 1)  ? Gp4   : 1.0;
    w4 *= (lane & 2)  ? Gp8   : 1.0;
    w4 *= (lane & 4)  ? Gp16  : 1.0;
    w4 *= (lane & 8)  ? Gp32  : 1.0;
    w4 *= (lane & 16) ? Gp64  : 1.0;
    w4 *= (lane & 32) ? Gp128 : 1.0;

    // ---- phase 0a: ep_rs loads FIRST (window k = wv, wv+8, 16; own chunk) --
    const int cc0 = c0 + 1 + wv;
    const int cc1 = c0 + 1 + wv + 8;
    const int cc2 = c0 + 1 + 16;
    float4 rv0 = (cc0 < NC) ? ((const float4*)r)[(size_t)cc0 * 64 + lane] : make_float4(0,0,0,0);
    float4 rv1 = (cc1 < NC) ? ((const float4*)r)[(size_t)cc1 * 64 + lane] : make_float4(0,0,0,0);
    float4 rv2 = (wv == 0 && cc2 < NC) ? ((const float4*)r)[(size_t)cc2 * 64 + lane] : make_float4(0,0,0,0);
    const float4 rown = (wv < CPB) ? ((const float4*)r)[(size_t)(c0 + wv) * 64 + lane] : make_float4(0,0,0,0);

    // ---- phase 0b: weight/act loads for this thread's 2 rows ----
    const size_t rowBase = (size_t)c0 * CHUNK;
    const float4* wp = (const float4*)(wgt + (rowBase + 2 * (size_t)tid) * A_DIM);
    float4 a[9];
    #pragma unroll
    for (int q = 0; q < 9; ++q) a[q] = wp[q];
    const int2 aa = *(const int2*)(act + rowBase + 2 * tid);

    // ---- phase 1: window chunk sums (3 independent reduces -> ILP) ----
    double vs0 = w4 * ((double)rv0.x + g * ((double)rv0.y + g * ((double)rv0.z + g * (double)rv0.w)));
    double vs1 = w4 * ((double)rv1.x + g * ((double)rv1.y + g * ((double)rv1.z + g * (double)rv1.w)));
    double vs2 = w4 * ((double)rv2.x + g * ((double)rv2.y + g * ((double)rv2.z + g * (double)rv2.w)));
    #pragma unroll
    for (int off = 32; off > 0; off >>= 1) {
        vs0 += __shfl_down(vs0, off, 64);
        vs1 += __shfl_down(vs1, off, 64);
        vs2 += __shfl_down(vs2, off, 64);
    }
    if (lane == 0) {
        ldsL[wv]     = vs0;                   // k = 0..7
        ldsL[wv + 8] = vs1;                   // k = 8..15
        if (wv == 0) ldsL[16] = vs2;          // k = 16
    }
    __syncthreads();

    // ---- phase 2: own-chunk d (waves 0..3), bit-exact lane suffix scan ----
    if (wv < CPB) {
        double acc_c = 0.0, wG = 1.0;
        #pragma unroll
        for (int m = 0; m < KTR; ++m) { acc_c += wG * ldsL[wv + m]; wG *= Gp256; }
        const double u3 = (double)rown.w;
        const double u2 = (double)rown.z + g * u3;
        const double u1 = (double)rown.y + g * u2;
        const double u0 = (double)rown.x + g * u1;
        double S = w4 * u0;
        #pragma unroll
        for (int off = 1; off < 64; off <<= 1) {
            const double t = __shfl_down(S, off, 64);
            S += (lane + off < 64) ? t : 0.0;
        }
        double Snext = __shfl_down(S, 1, 64);
        if (lane == 63) Snext = 0.0;
        const double A = (1.0 / w4) * (Snext + Gp256 * acc_c);
        double* dp = ldsD + wv * CHUNK + 4 * lane;
        dp[0] = u0 + A;
        dp[1] = u1 + IG * A;
        dp[2] = u2 + (IG * IG) * A;
        dp[3] = u3 + (IG * IG * IG) * A;
    }
    __syncthreads();

    // ---- phase 3: logsumexp on 2 rows (native transcendentals) ----
    const double2 dd = *(const double2*)(ldsD + 2 * tid);
    double s_n = 0.0, s_nd = 0.0;
    double s_d = dd.x + dd.y;
    float w[36];
    #pragma unroll
    for (int q = 0; q < 9; ++q) {
        w[4*q+0] = a[q].x; w[4*q+1] = a[q].y; w[4*q+2] = a[q].z; w[4*q+3] = a[q].w;
    }
    {   // row 0
        float mx = w[0];
        #pragma unroll
        for (int j = 1; j < A_DIM; ++j) mx = fmaxf(mx, w[j]);
        float s = 0.0f, wsel = 0.0f;
        #pragma unroll
        for (int j = 0; j < A_DIM; ++j) { s += __expf(w[j] - mx); wsel = (j == aa.x) ? w[j] : wsel; }
        const float nlp = mx + __logf(s) - wsel;
        s_n += (double)nlp;  s_nd += (double)nlp * dd.x;
    }
    {   // row 1
        float mx = w[18];
        #pragma unroll
        for (int j = 1; j < A_DIM; ++j) mx = fmaxf(mx, w[18 + j]);
        float s = 0.0f, wsel = 0.0f;
        #pragma unroll
        for (int j = 0; j < A_DIM; ++j) { s += __expf(w[18 + j] - mx); wsel = (j == aa.y) ? w[18 + j] : wsel; }
        const float nlp = mx + __logf(s) - wsel;
        s_n += (double)nlp;  s_nd += (double)nlp * dd.y;
    }

    // ---- epilogue: block reduce -> per-block partials (no atomics) ----
    #pragma unroll
    for (int off = 32; off > 0; off >>= 1) {
        s_d  += __shfl_down(s_d,  off, 64);
        s_n  += __shfl_down(s_n,  off, 64);
        s_nd += __shfl_down(s_nd, off, 64);
    }
    if (lane == 0) { red[wv*3+0] = s_d; red[wv*3+1] = s_n; red[wv*3+2] = s_nd; }
    __syncthreads();
    if (tid == 0) {
        double pa = 0.0, pb = 0.0, pc = 0.0;
        #pragma unroll
        for (int q = 0; q < 8; ++q) { pa += red[q*3]; pb += red[q*3+1]; pc += red[q*3+2]; }
        partials[blockIdx.x*3+0] = pa;
        partials[blockIdx.x*3+1] = pb;
        partials[blockIdx.x*3+2] = pc;
    }
}

// ---------------------------------------------------------------------------
// Final reduce: per-block partials -> scalar.
__global__ void k_final(const double* __restrict__ partials, float* __restrict__ out) {
    __shared__ double red[12];
    const int tid = threadIdx.x;
    double a = 0.0, b = 0.0, c = 0.0;
    for (int i = tid; i < NB; i += 256) {
        a += partials[i*3+0];
        b += partials[i*3+1];
        c += partials[i*3+2];
    }
    #pragma unroll
    for (int off = 32; off > 0; off >>= 1) {
        a += __shfl_down(a, off, 64);
        b += __shfl_down(b, off, 64);
        c += __shfl_down(c, off, 64);
    }
    const int lane = tid & 63, wv = tid >> 6;
    if (lane == 0) { red[wv*3+0] = a; red[wv*3+1] = b; red[wv*3+2] = c; }
    __syncthreads();
    if (tid == 0) {
        double A_ = 0.0, B_ = 0.0, C_ = 0.0;
        #pragma unroll
        for (int i = 0; i < 4; ++i) { A_ += red[i*3]; B_ += red[i*3+1]; C_ += red[i*3+2]; }
        const double invT = 1.0 / (double)T_TOTAL;
        // out = (1/T) * ( sum(nlp*d) - mean(d) * sum(nlp) )
        out[0] = (float)((C_ - (A_ * invT) * B_) * invT);
    }
}

// ---------------------------------------------------------------------------
extern "C" void kernel_launch(void* const* d_in, const int* in_sizes, int n_in,
                              void* d_out, int out_size, void* d_ws, size_t ws_size,
                              hipStream_t stream) {
    const float* weight = (const float*)d_in[0];   // [T, 18] f32
    const float* ep_rs  = (const float*)d_in[1];   // [T] f32
    const int*   ep_as  = (const int*)  d_in[2];   // [T] int
    float* out = (float*)d_out;

    double* partials = (double*)d_ws;              // NB*3 doubles (48 KiB)

    k_mega  <<<NB, BLK, 0, stream>>>(weight, ep_as, ep_rs, partials);
    k_final <<<1,  256, 0, stream>>>(partials, out);
}

// Round 10
// 236.636 us; speedup vs baseline: 1.0938x; 1.0938x over previous
//
#include <hip/hip_runtime.h>
#include <math.h>

// Problem constants (from setup_inputs)
#define T_TOTAL 2097152
#define A_DIM   18
#define GAMMA_D 0.99

#define CHUNK 256
#define NC    (T_TOTAL / CHUNK)        // 8192 chunks
#define KTR   14                       // G^14 ~ 2e-16, G = 0.99^256 ~ 0.076
#define CPB   2                        // chunks per block
#define NB    (NC / CPB)               // 4096 blocks
#define BLK   256                      // 4 waves; 2 rows/thread
#define WIN   (CPB + KTR - 1)          // 15-chunk carry window

// Compile-time powers of gamma (no ocml pow: saves ~300 f64 ops + scratch).
constexpr double Gp1   = GAMMA_D;
constexpr double Gp2   = Gp1 * Gp1;
constexpr double Gp4   = Gp2 * Gp2;
constexpr double Gp8   = Gp4 * Gp4;
constexpr double Gp16  = Gp8 * Gp8;
constexpr double Gp32  = Gp16 * Gp16;
constexpr double Gp64  = Gp32 * Gp32;
constexpr double Gp128 = Gp64 * Gp64;
constexpr double Gp256 = Gp128 * Gp128;  // g^256 (per-chunk decay)
constexpr double IG    = 1.0 / GAMMA_D;

// ---------------------------------------------------------------------------
// Fused kernel, register-lifetime-disjoint phases (R9 post-mortem: holding
// r-window AND weight tiles live needs ~85+ VGPR; under a 64-reg cap the
// compiler spilled 113 MB/dispatch to scratch. Fix: r-phase fully retires
// into LDS before any weight load is issued -> peak live set ~60 regs).
//   phase 0: r loads (window 15 chunks + own chunk for waves 0-1)
//   phase 1: window chunk-sums -> ldsL[15]
//   phase 2: waves 0-1 compute own-chunk d (bit-exact scan) -> ldsD[512]
//   phase 3: weight/act loads + register logsumexp on 2 consecutive rows
//   epilogue: block reduce -> partials (atomics proven bad in R6/R7)
// __launch_bounds__(256,6): VGPR cap 85 (512-reg SIMD pool / 6 waves),
// 6 waves/SIMD = 75% occupancy target, no-spill margin over the ~60-reg peak.
__global__ __launch_bounds__(BLK, 6)
void k_mega(const float* __restrict__ wgt, const int* __restrict__ act,
            const float* __restrict__ r, double* __restrict__ partials) {
    __shared__ double ldsL[WIN];              // window chunk-sums
    __shared__ double ldsD[CPB * CHUNK];      // d for the block's 512 rows (4 KB)
    __shared__ double red[12];
    const int tid  = threadIdx.x;
    const int lane = tid & 63, wv = tid >> 6;      // wv in 0..3
    const int c0   = blockIdx.x * CPB;
    const double g = GAMMA_D;
    // w4 = g^(4*lane) via bit-product (6 mult+select)
    double w4 = 1.0;
    w4 *= (lane & 1)  ? Gp4   : 1.0;
    w4 *= (lane & 2)  ? Gp8   : 1.0;
    w4 *= (lane & 4)  ? Gp16  : 1.0;
    w4 *= (lane & 8)  ? Gp32  : 1.0;
    w4 *= (lane & 16) ? Gp64  : 1.0;
    w4 *= (lane & 32) ? Gp128 : 1.0;

    // ---- phase 0: r loads only (window k = wv+4i < 15; own chunk wv<2) ----
    float4 rwin[4];
    #pragma unroll
    for (int i = 0; i < 4; ++i) {
        const int k  = wv + 4 * i;
        const int cc = c0 + 1 + k;
        rwin[i] = (k < WIN && cc < NC)         // wave-uniform guard
                  ? ((const float4*)r)[(size_t)cc * 64 + lane]
                  : make_float4(0, 0, 0, 0);
    }
    const float4 rown = (wv < CPB)
                        ? ((const float4*)r)[(size_t)(c0 + wv) * 64 + lane]
                        : make_float4(0, 0, 0, 0);

    // ---- phase 1: window chunk sums -> ldsL ----
    #pragma unroll
    for (int i = 0; i < 4; ++i) {
        const int k = wv + 4 * i;
        if (k < WIN) {
            double val = w4 * ((double)rwin[i].x + g * ((double)rwin[i].y +
                         g * ((double)rwin[i].z + g * (double)rwin[i].w)));
            #pragma unroll
            for (int off = 32; off > 0; off >>= 1) val += __shfl_down(val, off, 64);
            if (lane == 0) ldsL[k] = val;
        }
    }
    __syncthreads();

    // ---- phase 2: own-chunk d (waves 0..1), bit-exact lane suffix scan ----
    if (wv < CPB) {
        double acc_c = 0.0, wG = 1.0;
        #pragma unroll
        for (int m = 0; m < KTR; ++m) { acc_c += wG * ldsL[wv + m]; wG *= Gp256; }
        const double u3 = (double)rown.w;
        const double u2 = (double)rown.z + g * u3;
        const double u1 = (double)rown.y + g * u2;
        const double u0 = (double)rown.x + g * u1;
        double S = w4 * u0;
        #pragma unroll
        for (int off = 1; off < 64; off <<= 1) {
            const double t = __shfl_down(S, off, 64);
            S += (lane + off < 64) ? t : 0.0;
        }
        double Snext = __shfl_down(S, 1, 64);
        if (lane == 63) Snext = 0.0;
        const double A = (1.0 / w4) * (Snext + Gp256 * acc_c);
        double* dp = ldsD + wv * CHUNK + 4 * lane;
        dp[0] = u0 + A;
        dp[1] = u1 + IG * A;
        dp[2] = u2 + (IG * IG) * A;
        dp[3] = u3 + (IG * IG * IG) * A;
    }
    __syncthreads();

    // ---- phase 3: weight loads + logsumexp (r-phase registers now dead) ----
    const size_t t0 = (size_t)blockIdx.x * (CPB * CHUNK) + 2 * (size_t)tid;
    float w[36];                               // single live copy (float4 alias)
    float4* aw = (float4*)w;
    const float4* wp = (const float4*)(wgt + t0 * A_DIM);
    #pragma unroll
    for (int q = 0; q < 9; ++q) aw[q] = wp[q];
    const int2    aa = *(const int2*)(act + t0);
    const double2 dd = *(const double2*)(ldsD + 2 * tid);

    double s_n = 0.0, s_nd = 0.0;
    double s_d = dd.x + dd.y;
    {   // row 0 (exact op order; native transcendentals)
        float mx = w[0];
        #pragma unroll
        for (int j = 1; j < A_DIM; ++j) mx = fmaxf(mx, w[j]);
        float s = 0.0f, wsel = 0.0f;
        #pragma unroll
        for (int j = 0; j < A_DIM; ++j) { s += __expf(w[j] - mx); wsel = (j == aa.x) ? w[j] : wsel; }
        const float nlp = mx + __logf(s) - wsel;
        s_n += (double)nlp;  s_nd += (double)nlp * dd.x;
    }
    {   // row 1
        float mx = w[18];
        #pragma unroll
        for (int j = 1; j < A_DIM; ++j) mx = fmaxf(mx, w[18 + j]);
        float s = 0.0f, wsel = 0.0f;
        #pragma unroll
        for (int j = 0; j < A_DIM; ++j) { s += __expf(w[18 + j] - mx); wsel = (j == aa.y) ? w[18 + j] : wsel; }
        const float nlp = mx + __logf(s) - wsel;
        s_n += (double)nlp;  s_nd += (double)nlp * dd.y;
    }

    // ---- epilogue: block reduce -> per-block partials ----
    #pragma unroll
    for (int off = 32; off > 0; off >>= 1) {
        s_d  += __shfl_down(s_d,  off, 64);
        s_n  += __shfl_down(s_n,  off, 64);
        s_nd += __shfl_down(s_nd, off, 64);
    }
    if (lane == 0) { red[wv*3+0] = s_d; red[wv*3+1] = s_n; red[wv*3+2] = s_nd; }
    __syncthreads();
    if (tid == 0) {
        double pa = 0.0, pb = 0.0, pc = 0.0;
        #pragma unroll
        for (int q = 0; q < 4; ++q) { pa += red[q*3]; pb += red[q*3+1]; pc += red[q*3+2]; }
        partials[blockIdx.x*3+0] = pa;
        partials[blockIdx.x*3+1] = pb;
        partials[blockIdx.x*3+2] = pc;
    }
}

// ---------------------------------------------------------------------------
// Final reduce: per-block partials -> scalar.
__global__ void k_final(const double* __restrict__ partials, float* __restrict__ out) {
    __shared__ double red[12];
    const int tid = threadIdx.x;
    double a = 0.0, b = 0.0, c = 0.0;
    for (int i = tid; i < NB; i += 256) {
        a += partials[i*3+0];
        b += partials[i*3+1];
        c += partials[i*3+2];
    }
    #pragma unroll
    for (int off = 32; off > 0; off >>= 1) {
        a += __shfl_down(a, off, 64);
        b += __shfl_down(b, off, 64);
        c += __shfl_down(c, off, 64);
    }
    const int lane = tid & 63, wv = tid >> 6;
    if (lane == 0) { red[wv*3+0] = a; red[wv*3+1] = b; red[wv*3+2] = c; }
    __syncthreads();
    if (tid == 0) {
        double A_ = 0.0, B_ = 0.0, C_ = 0.0;
        #pragma unroll
        for (int i = 0; i < 4; ++i) { A_ += red[i*3]; B_ += red[i*3+1]; C_ += red[i*3+2]; }
        const double invT = 1.0 / (double)T_TOTAL;
        // out = (1/T) * ( sum(nlp*d) - mean(d) * sum(nlp) )
        out[0] = (float)((C_ - (A_ * invT) * B_) * invT);
    }
}

// ---------------------------------------------------------------------------
extern "C" void kernel_launch(void* const* d_in, const int* in_sizes, int n_in,
                              void* d_out, int out_size, void* d_ws, size_t ws_size,
                              hipStream_t stream) {
    const float* weight = (const float*)d_in[0];   // [T, 18] f32
    const float* ep_rs  = (const float*)d_in[1];   // [T] f32
    const int*   ep_as  = (const int*)  d_in[2];   // [T] int
    float* out = (float*)d_out;

    double* partials = (double*)d_ws;              // NB*3 doubles (96 KiB)

    k_mega  <<<NB, BLK, 0, stream>>>(weight, ep_as, ep_rs, partials);
    k_final <<<1,  256, 0, stream>>>(partials, out);
}

// Round 11
// 236.324 us; speedup vs baseline: 1.0952x; 1.0013x over previous
//
#include <hip/hip_runtime.h>
#include <math.h>

// Problem constants (from setup_inputs)
#define T_TOTAL 2097152
#define A_DIM   18
#define GAMMA_D 0.99

#define CHUNK 256
#define NC    (T_TOTAL / CHUNK)        // 8192 chunks
#define KTR   14                       // G^14 ~ 2e-16, G = 0.99^256 ~ 0.076
#define CPB   8                        // chunks per block
#define NB    (NC / CPB)               // 1024 blocks == 4 per CU, ALL resident
#define BLK   256                      // 4 waves
#define WIN   (CPB + KTR - 1)          // 21-chunk carry window
#define ITERS (CPB * CHUNK / (BLK * 2))// 4 streaming iterations (2 rows/thread)

// Compile-time powers of gamma (no ocml pow).
constexpr double Gp1   = GAMMA_D;
constexpr double Gp2   = Gp1 * Gp1;
constexpr double Gp4   = Gp2 * Gp2;
constexpr double Gp8   = Gp4 * Gp4;
constexpr double Gp16  = Gp8 * Gp8;
constexpr double Gp32  = Gp16 * Gp16;
constexpr double Gp64  = Gp32 * Gp32;
constexpr double Gp128 = Gp64 * Gp64;
constexpr double Gp256 = Gp128 * Gp128;  // g^256 (per-chunk decay)
constexpr double IG    = 1.0 / GAMMA_D;

// ---------------------------------------------------------------------------
// Fully-resident pipelined kernel (R10 post-mortem: all prior variants pay the
// r-phase/weight-burst serialization 8 batches deep and stream weights in one
// un-pipelined burst; k_mega sat ~2x over its 25us traffic floor).
//   - 1024 blocks = exactly 4/CU resident: zero batch turnover, launch ramp
//     and phase dead-time paid ONCE.
//   - phases 0-2 (r window sums -> 8-chunk d scan -> ldsD, 16 KB) run once,
//     amortized over 2048 rows.
//   - phase 3: 4 iterations x 512 rows, register double-buffered weight
//     stream (load it+1 while lse of it) — no barriers, no LDS traffic for
//     weights, continuous global-load issue.
// Register budget: wA+wB = 72 + scratch ~40 -> ~114 live < 128 cap (256,4).
// Spill canary: k_mega WRITE_SIZE must stay ~0.02 MB.
__global__ __launch_bounds__(BLK, 4)
void k_mega(const float* __restrict__ wgt, const int* __restrict__ act,
            const float* __restrict__ r, double* __restrict__ partials) {
    __shared__ double ldsL[WIN];              // window chunk-sums
    __shared__ double ldsD[CPB * CHUNK];      // d for the block's 2048 rows (16 KB)
    __shared__ double red[12];
    const int tid  = threadIdx.x;
    const int lane = tid & 63, wv = tid >> 6;      // wv in 0..3
    const int c0   = blockIdx.x * CPB;
    const double g = GAMMA_D;
    // w4 = g^(4*lane) via bit-product
    double w4 = 1.0;
    w4 *= (lane & 1)  ? Gp4   : 1.0;
    w4 *= (lane & 2)  ? Gp8   : 1.0;
    w4 *= (lane & 4)  ? Gp16  : 1.0;
    w4 *= (lane & 8)  ? Gp32  : 1.0;
    w4 *= (lane & 16) ? Gp64  : 1.0;
    w4 *= (lane & 32) ? Gp128 : 1.0;

    // ---- phase 0: issue ALL r loads (window k = wv+4i < 21; own 2 chunks) --
    float4 rwin[6];
    #pragma unroll
    for (int i = 0; i < 6; ++i) {
        const int k  = wv + 4 * i;
        const int cc = c0 + 1 + k;
        rwin[i] = (k < WIN && cc < NC)         // wave-uniform guard
                  ? ((const float4*)r)[(size_t)cc * 64 + lane]
                  : make_float4(0, 0, 0, 0);
    }
    float4 rown[2];
    #pragma unroll
    for (int jj = 0; jj < 2; ++jj)
        rown[jj] = ((const float4*)r)[(size_t)(c0 + wv + 4 * jj) * 64 + lane];

    // ---- phase 1: window chunk sums -> ldsL[21] ----
    #pragma unroll
    for (int i = 0; i < 6; ++i) {
        const int k = wv + 4 * i;
        if (k < WIN) {
            double val = w4 * ((double)rwin[i].x + g * ((double)rwin[i].y +
                         g * ((double)rwin[i].z + g * (double)rwin[i].w)));
            #pragma unroll
            for (int off = 32; off > 0; off >>= 1) val += __shfl_down(val, off, 64);
            if (lane == 0) ldsL[k] = val;
        }
    }
    __syncthreads();

    // ---- phase 2: d for chunks c0+wv, c0+wv+4 (bit-exact lane scan) ----
    #pragma unroll
    for (int jj = 0; jj < 2; ++jj) {
        const int j = wv + 4 * jj;             // chunk offset 0..7
        double acc_c = 0.0, wG = 1.0;
        #pragma unroll
        for (int m = 0; m < KTR; ++m) { acc_c += wG * ldsL[j + m]; wG *= Gp256; }
        const float4 v = rown[jj];
        const double u3 = (double)v.w;
        const double u2 = (double)v.z + g * u3;
        const double u1 = (double)v.y + g * u2;
        const double u0 = (double)v.x + g * u1;
        double S = w4 * u0;
        #pragma unroll
        for (int off = 1; off < 64; off <<= 1) {
            const double t = __shfl_down(S, off, 64);
            S += (lane + off < 64) ? t : 0.0;
        }
        double Snext = __shfl_down(S, 1, 64);
        if (lane == 63) Snext = 0.0;
        const double A = (1.0 / w4) * (Snext + Gp256 * acc_c);
        double* dp = ldsD + j * CHUNK + 4 * lane;
        dp[0] = u0 + A;
        dp[1] = u1 + IG * A;
        dp[2] = u2 + (IG * IG) * A;
        dp[3] = u3 + (IG * IG * IG) * A;
    }
    __syncthreads();                           // last barrier; stream phase is free-running

    // ---- phase 3: register double-buffered weight stream ----
    const size_t base = (size_t)c0 * CHUNK;
    double s_d = 0.0, s_n = 0.0, s_nd = 0.0;

    auto loadw = [&](float (&wb)[36], int2& aab, int it) {
        const size_t t0 = base + (size_t)it * 512 + 2 * (size_t)tid;
        const float4* wp = (const float4*)(wgt + t0 * A_DIM);
        float4* dst = (float4*)wb;
        #pragma unroll
        for (int q = 0; q < 9; ++q) dst[q] = wp[q];
        aab = *(const int2*)(act + t0);
    };
    auto lse2 = [&](const float (&wb)[36], const int2& aab, int it) {
        const double2 dd = *(const double2*)(ldsD + it * 512 + 2 * tid);
        s_d += dd.x + dd.y;
        {   // row 0 (exact op order; native transcendentals — R8-verified)
            float mx = wb[0];
            #pragma unroll
            for (int j = 1; j < A_DIM; ++j) mx = fmaxf(mx, wb[j]);
            float s = 0.0f, wsel = 0.0f;
            #pragma unroll
            for (int j = 0; j < A_DIM; ++j) { s += __expf(wb[j] - mx); wsel = (j == aab.x) ? wb[j] : wsel; }
            const float nlp = mx + __logf(s) - wsel;
            s_n += (double)nlp;  s_nd += (double)nlp * dd.x;
        }
        {   // row 1
            float mx = wb[18];
            #pragma unroll
            for (int j = 1; j < A_DIM; ++j) mx = fmaxf(mx, wb[18 + j]);
            float s = 0.0f, wsel = 0.0f;
            #pragma unroll
            for (int j = 0; j < A_DIM; ++j) { s += __expf(wb[18 + j] - mx); wsel = (j == aab.y) ? wb[18 + j] : wsel; }
            const float nlp = mx + __logf(s) - wsel;
            s_n += (double)nlp;  s_nd += (double)nlp * dd.y;
        }
    };

    float wA[36], wB[36];
    int2 aaA, aaB;
    loadw(wA, aaA, 0);                 // prologue
    loadw(wB, aaB, 1);  lse2(wA, aaA, 0);   // it 0: issue 1, compute 0
    loadw(wA, aaA, 2);  lse2(wB, aaB, 1);   // it 1: issue 2, compute 1
    loadw(wB, aaB, 3);  lse2(wA, aaA, 2);   // it 2: issue 3, compute 2
    lse2(wB, aaB, 3);                        // it 3: drain

    // ---- epilogue: block reduce -> per-block partials ----
    #pragma unroll
    for (int off = 32; off > 0; off >>= 1) {
        s_d  += __shfl_down(s_d,  off, 64);
        s_n  += __shfl_down(s_n,  off, 64);
        s_nd += __shfl_down(s_nd, off, 64);
    }
    if (lane == 0) { red[wv*3+0] = s_d; red[wv*3+1] = s_n; red[wv*3+2] = s_nd; }
    __syncthreads();
    if (tid == 0) {
        double pa = 0.0, pb = 0.0, pc = 0.0;
        #pragma unroll
        for (int q = 0; q < 4; ++q) { pa += red[q*3]; pb += red[q*3+1]; pc += red[q*3+2]; }
        partials[blockIdx.x*3+0] = pa;
        partials[blockIdx.x*3+1] = pb;
        partials[blockIdx.x*3+2] = pc;
    }
}

// ---------------------------------------------------------------------------
// Final reduce: per-block partials -> scalar.
__global__ void k_final(const double* __restrict__ partials, float* __restrict__ out) {
    __shared__ double red[12];
    const int tid = threadIdx.x;
    double a = 0.0, b = 0.0, c = 0.0;
    for (int i = tid; i < NB; i += 256) {
        a += partials[i*3+0];
        b += partials[i*3+1];
        c += partials[i*3+2];
    }
    #pragma unroll
    for (int off = 32; off > 0; off >>= 1) {
        a += __shfl_down(a, off, 64);
        b += __shfl_down(b, off, 64);
        c += __shfl_down(c, off, 64);
    }
    const int lane = tid & 63, wv = tid >> 6;
    if (lane == 0) { red[wv*3+0] = a; red[wv*3+1] = b; red[wv*3+2] = c; }
    __syncthreads();
    if (tid == 0) {
        double A_ = 0.0, B_ = 0.0, C_ = 0.0;
        #pragma unroll
        for (int i = 0; i < 4; ++i) { A_ += red[i*3]; B_ += red[i*3+1]; C_ += red[i*3+2]; }
        const double invT = 1.0 / (double)T_TOTAL;
        // out = (1/T) * ( sum(nlp*d) - mean(d) * sum(nlp) )
        out[0] = (float)((C_ - (A_ * invT) * B_) * invT);
    }
}

// ---------------------------------------------------------------------------
extern "C" void kernel_launch(void* const* d_in, const int* in_sizes, int n_in,
                              void* d_out, int out_size, void* d_ws, size_t ws_size,
                              hipStream_t stream) {
    const float* weight = (const float*)d_in[0];   // [T, 18] f32
    const float* ep_rs  = (const float*)d_in[1];   // [T] f32
    const int*   ep_as  = (const int*)  d_in[2];   // [T] int
    float* out = (float*)d_out;

    double* partials = (double*)d_ws;              // NB*3 doubles (24 KiB)

    k_mega  <<<NB, BLK, 0, stream>>>(weight, ep_as, ep_rs, partials);
    k_final <<<1,  256, 0, stream>>>(partials, out);
}

// Round 12
// 230.803 us; speedup vs baseline: 1.1214x; 1.0239x over previous
//
#include <hip/hip_runtime.h>
#include <math.h>

// Problem constants (from setup_inputs)
#define T_TOTAL 2097152
#define A_DIM   18
#define GAMMA_D 0.99

#define CHUNK 256
#define NC    (T_TOTAL / CHUNK)        // 8192 chunks
#define KTR   14                       // G^14 ~ 2e-16, G = 0.99^256 ~ 0.076
#define CPB   4                        // chunks per block
#define NB    (NC / CPB)               // 2048 blocks

// ---------------------------------------------------------------------------
// R8 champion (231.9 us, absmax 0.0): R5-proven fused structure + native
// transcendentals. Session ledger (R1-R11): nine structural variants span
// 232-240 us; the timed window is ~176 us harness poison-fills at 85-87% of
// achievable HBM BW + ~56 us ours, structure-invariant. This is the floor.
__global__ __launch_bounds__(256, 4)
void k_mega(const float* __restrict__ wgt, const int* __restrict__ act,
            const float* __restrict__ r, double* __restrict__ partials) {
    __shared__ double ldsL[17];               // window chunk-sums
    __shared__ double ldsD[CPB * CHUNK];      // d for the block's 1024 rows (8 KB)
    __shared__ double red[12];
    const int tid  = threadIdx.x;
    const int lane = tid & 63, wv = tid >> 6;
    const int c0   = blockIdx.x * CPB;
    const double g  = GAMMA_D;
    const double G_ = pow(g, 256.0);
    const double w4 = pow(g, (double)(4 * lane));

    // ---- phase 0: issue pair-0 weight/act loads early ----
    const size_t rowBase = (size_t)c0 * CHUNK;
    const float4* wp0 = (const float4*)(wgt + (rowBase + 2 * (size_t)tid) * A_DIM);
    float4 a0[9];
    #pragma unroll
    for (int q = 0; q < 9; ++q) a0[q] = wp0[q];
    const int2 aa0 = *(const int2*)(act + rowBase + 2 * tid);

    // ---- phase 1: window L (wave wv handles k = wv, wv+4, ...) ----
    #pragma unroll
    for (int i = 0; i < 5; ++i) {
        const int k  = wv + 4 * i;
        const int cc = c0 + 1 + k;
        if (k < 17) {
            double val = 0.0;
            if (cc < NC) {                    // wave-uniform guard
                const float4 v = ((const float4*)r)[(size_t)cc * 64 + lane];
                val = w4 * ((double)v.x + g * ((double)v.y + g * ((double)v.z + g * (double)v.w)));
                #pragma unroll
                for (int off = 32; off > 0; off >>= 1) val += __shfl_down(val, off, 64);
            }
            if (lane == 0) ldsL[k] = val;
        }
    }
    __syncthreads();

    // ---- phase 2: own-chunk d (wave wv -> chunk c0+wv), bit-exact scan ----
    {
        double acc = 0.0, wG = 1.0;
        #pragma unroll
        for (int m = 0; m < KTR; ++m) { acc += wG * ldsL[wv + m]; wG *= G_; }
        const int c = c0 + wv;
        const float4 v = ((const float4*)r)[(size_t)c * 64 + lane];
        const double u3 = (double)v.w;
        const double u2 = (double)v.z + g * u3;
        const double u1 = (double)v.y + g * u2;
        const double u0 = (double)v.x + g * u1;
        double S = w4 * u0;
        #pragma unroll
        for (int off = 1; off < 64; off <<= 1) {
            const double t = __shfl_down(S, off, 64);
            S += (lane + off < 64) ? t : 0.0;
        }
        double Snext = __shfl_down(S, 1, 64);
        if (lane == 63) Snext = 0.0;
        const double A  = (1.0 / w4) * (Snext + G_ * acc);
        const double ig = 1.0 / g;
        double* dp = ldsD + wv * CHUNK + 4 * lane;
        dp[0] = u0 + A;
        dp[1] = u1 + ig * A;
        dp[2] = u2 + (ig * ig) * A;
        dp[3] = u3 + (ig * ig * ig) * A;
    }
    __syncthreads();

    // ---- phase 3: logsumexp on two row-pairs (native transcendentals) ----
    const float4* wp1 = (const float4*)(wgt + (rowBase + 512 + 2 * (size_t)tid) * A_DIM);
    float4 a1[9];
    #pragma unroll
    for (int q = 0; q < 9; ++q) a1[q] = wp1[q];
    const int2    aa1 = *(const int2*)(act + rowBase + 512 + 2 * tid);
    const double2 dd0 = *(const double2*)(ldsD + 2 * tid);
    const double2 dd1 = *(const double2*)(ldsD + 512 + 2 * tid);

    double s_n = 0.0, s_nd = 0.0;
    double s_d = dd0.x + dd0.y + dd1.x + dd1.y;
    float w[36];
    // pair 0
    #pragma unroll
    for (int q = 0; q < 9; ++q) {
        w[4*q+0] = a0[q].x; w[4*q+1] = a0[q].y; w[4*q+2] = a0[q].z; w[4*q+3] = a0[q].w;
    }
    {   // row 0
        float mx = w[0];
        #pragma unroll
        for (int j = 1; j < A_DIM; ++j) mx = fmaxf(mx, w[j]);
        float s = 0.0f, wsel = 0.0f;
        #pragma unroll
        for (int j = 0; j < A_DIM; ++j) { s += __expf(w[j] - mx); wsel = (j == aa0.x) ? w[j] : wsel; }
        const float nlp = mx + __logf(s) - wsel;
        s_n += (double)nlp;  s_nd += (double)nlp * dd0.x;
    }
    {   // row 1
        float mx = w[18];
        #pragma unroll
        for (int j = 1; j < A_DIM; ++j) mx = fmaxf(mx, w[18 + j]);
        float s = 0.0f, wsel = 0.0f;
        #pragma unroll
        for (int j = 0; j < A_DIM; ++j) { s += __expf(w[18 + j] - mx); wsel = (j == aa0.y) ? w[18 + j] : wsel; }
        const float nlp = mx + __logf(s) - wsel;
        s_n += (double)nlp;  s_nd += (double)nlp * dd0.y;
    }
    // pair 1
    #pragma unroll
    for (int q = 0; q < 9; ++q) {
        w[4*q+0] = a1[q].x; w[4*q+1] = a1[q].y; w[4*q+2] = a1[q].z; w[4*q+3] = a1[q].w;
    }
    {   // row 2
        float mx = w[0];
        #pragma unroll
        for (int j = 1; j < A_DIM; ++j) mx = fmaxf(mx, w[j]);
        float s = 0.0f, wsel = 0.0f;
        #pragma unroll
        for (int j = 0; j < A_DIM; ++j) { s += __expf(w[j] - mx); wsel = (j == aa1.x) ? w[j] : wsel; }
        const float nlp = mx + __logf(s) - wsel;
        s_n += (double)nlp;  s_nd += (double)nlp * dd1.x;
    }
    {   // row 3
        float mx = w[18];
        #pragma unroll
        for (int j = 1; j < A_DIM; ++j) mx = fmaxf(mx, w[18 + j]);
        float s = 0.0f, wsel = 0.0f;
        #pragma unroll
        for (int j = 0; j < A_DIM; ++j) { s += __expf(w[18 + j] - mx); wsel = (j == aa1.y) ? w[18 + j] : wsel; }
        const float nlp = mx + __logf(s) - wsel;
        s_n += (double)nlp;  s_nd += (double)nlp * dd1.y;
    }

    // block reduction
    #pragma unroll
    for (int off = 32; off > 0; off >>= 1) {
        s_d  += __shfl_down(s_d,  off, 64);
        s_n  += __shfl_down(s_n,  off, 64);
        s_nd += __shfl_down(s_nd, off, 64);
    }
    if (lane == 0) { red[wv*3+0] = s_d; red[wv*3+1] = s_n; red[wv*3+2] = s_nd; }
    __syncthreads();
    if (tid == 0) {
        double a = 0.0, b = 0.0, cc = 0.0;
        #pragma unroll
        for (int q = 0; q < 4; ++q) { a += red[q*3]; b += red[q*3+1]; cc += red[q*3+2]; }
        partials[blockIdx.x*3+0] = a;
        partials[blockIdx.x*3+1] = b;
        partials[blockIdx.x*3+2] = cc;
    }
}

// ---------------------------------------------------------------------------
// Final reduce: per-block partials -> scalar.
__global__ void k_final(const double* __restrict__ partials, float* __restrict__ out) {
    __shared__ double red[12];
    const int tid = threadIdx.x;
    double a = 0.0, b = 0.0, c = 0.0;
    for (int i = tid; i < NB; i += 256) {
        a += partials[i*3+0];
        b += partials[i*3+1];
        c += partials[i*3+2];
    }
    #pragma unroll
    for (int off = 32; off > 0; off >>= 1) {
        a += __shfl_down(a, off, 64);
        b += __shfl_down(b, off, 64);
        c += __shfl_down(c, off, 64);
    }
    const int lane = tid & 63, wv = tid >> 6;
    if (lane == 0) { red[wv*3+0] = a; red[wv*3+1] = b; red[wv*3+2] = c; }
    __syncthreads();
    if (tid == 0) {
        double A_ = 0.0, B_ = 0.0, C_ = 0.0;
        #pragma unroll
        for (int i = 0; i < 4; ++i) { A_ += red[i*3]; B_ += red[i*3+1]; C_ += red[i*3+2]; }
        const double invT = 1.0 / (double)T_TOTAL;
        // out = (1/T) * ( sum(nlp*d) - mean(d) * sum(nlp) )
        out[0] = (float)((C_ - (A_ * invT) * B_) * invT);
    }
}

// ---------------------------------------------------------------------------
extern "C" void kernel_launch(void* const* d_in, const int* in_sizes, int n_in,
                              void* d_out, int out_size, void* d_ws, size_t ws_size,
                              hipStream_t stream) {
    const float* weight = (const float*)d_in[0];   // [T, 18] f32
    const float* ep_rs  = (const float*)d_in[1];   // [T] f32
    const int*   ep_as  = (const int*)  d_in[2];   // [T] int
    float* out = (float*)d_out;

    double* partials = (double*)d_ws;              // NB*3 doubles (48 KiB)

    k_mega  <<<NB, 256, 0, stream>>>(weight, ep_as, ep_rs, partials);
    k_final <<<1,  256, 0, stream>>>(partials, out);
}